// Round 7
// baseline (398.077 us; speedup 1.0000x reference)
//
#include <hip/hip_runtime.h>
#include <stdint.h>

typedef unsigned long long u64;
typedef unsigned short u16;
typedef unsigned int u32;
typedef float nfloat4 __attribute__((ext_vector_type(4)));  // native vec for nt-store

#define LQ   4096
#define BQ   8
#define KNB  16
#define TPB  512
#define QPB  64                  // queries per block, 8 lanes each
#define BPB  (LQ / QPB)          // 64 blocks per batch
#define NBK  112                 // histogram buckets (8/octave, d^2 in [2^-10, 2^4))
#define HBASE 936u               // (127-10)<<3 : bucket base for d^2 = 2^-10
#define LCAP 64                  // per-query collect capacity

// f64 compare-exchange (exact 44-bit keys as positive denormals; u64 order ==
// f64 order for these, denormals never flushed on CDNA — verified r1..r6)
__device__ __forceinline__ void ced(double &a, double &b) {
    const double mn = __builtin_fmin(a, b);
    const double mx = __builtin_fmax(a, b);
    a = mn; b = mx;
}
// bit-exact vs reference: no FMA, sum order (x^2+y^2)+z^2  (re-rank only)
__device__ __forceinline__ float dist2(float mx, float my, float mz,
                                       float px, float py, float pz) {
    const float dx = __fsub_rn(mx, px);
    const float dy = __fsub_rn(my, py);
    const float dz = __fsub_rn(mz, pz);
    return __fadd_rn(__fadd_rn(__fmul_rn(dx, dx), __fmul_rn(dy, dy)),
                     __fmul_rn(dz, dz));
}

// Selection: per-query histogram of (fma-d^2 bits >> 20) -> smallest bucket T
// with cum >= 16, threshold T+1 (one-bucket slack). Collected superset then
// re-ranked EXACTLY with ((u64)d_bits<<12)|j keys (non-FMA dist, reference
// tie-break). Margin vs fma-vs-exact reorder is a full 2^20-ulp bucket —
// strictly wider than the verified r2-r6 truncated-key construction.

__global__ __launch_bounds__(TPB) void knn_fused_kernel(
    const float4* __restrict__ frame4,   // (B, L, 3) float4 view of (B,L,4,3)
    const float4* __restrict__ attr4,    // (B, L, 32) float4 view of (B,L,128)
    float* __restrict__ out_e,           // (B, L, 16, 3)
    nfloat4* __restrict__ outg4)         // (B, L, 16, 32) float4
{
    __shared__ float2 pxy[LQ];           // 32 KB
    __shared__ float  pz[LQ];            // 16 KB
    __shared__ u32    hist[32 * NBK];    // 14 KB  (qpair-major, 2 queries/u32)
    __shared__ u16    list[QPB][LCAP];   // 8 KB   per-query collected cand idx
    __shared__ u32    cnt[QPB];          // 256 B
    __shared__ int    nbrs[QPB][KNB];    // 4 KB   final neighbor idx
    // total 74.25 KB -> exactly 2 blocks/CU, grid 512 = 2*256: zero tail

    const int b    = blockIdx.x >> 6;    // 64 blocks per batch
    const int qblk = blockIdx.x & (BPB - 1);
    const int tid  = threadIdx.x;
    const int wv   = tid >> 6;           // wave 0..7
    const int lane = tid & 63;

    const float4* fb = frame4 + (size_t)b * LQ * 3;
    for (int j = tid; j < LQ; j += TPB) {
        const float4 v = fb[j * 3];
        pxy[j] = make_float2(v.x, v.y);
        pz[j]  = v.z;
    }
    // wave-private clears (hist columns / cnt rows owned by this wave only)
    for (int t = lane; t < 4 * NBK; t += 64) hist[wv * 4 * NBK + t] = 0u;
    if (lane < 8) cnt[wv * 8 + lane] = 0u;
    __syncthreads();   // only barrier: waves are independent afterwards

    const int qloc = tid >> 3;           // 0..63
    const int h    = tid & 7;            // sub-stream within query
    const int l    = qblk * QPB + qloc;
    const float2 mxy = pxy[l];
    const float mx = mxy.x, my = mxy.y, mz = pz[l];

    const u32 qp     = (u32)(qloc >> 1);
    const u32 sh     = (u32)((qloc & 1) << 4);
    const u32 addend = 1u << sh;
    const u32 hb     = qp * NBK;

    // ---- pass 1: histogram (no loop-carried deps, branch-free) ----
#pragma unroll 1
    for (int cc = 0; cc < 64; ++cc) {
#pragma unroll
        for (int s = 0; s < 8; ++s) {
            const int j = cc * 64 + s * 8 + h;
            const float2 xy = pxy[j];
            const float  z  = pz[j];
            const float dx = __fsub_rn(mx, xy.x);
            const float dy = __fsub_rn(my, xy.y);
            const float dz = __fsub_rn(mz, z);
            const float d  = __fmaf_rn(dz, dz, __fmaf_rn(dy, dy, __fmul_rn(dx, dx)));
            int k = (int)(__float_as_uint(d) >> 20) - (int)HBASE;
            k = k < 0 ? 0 : (k > (NBK - 1) ? (NBK - 1) : k);
            atomicAdd(&hist[hb + (u32)k], addend);
        }
    }

    // ---- threshold: smallest T with cum >= 16, then +1 bucket slack ----
    const int b0 = h * (NBK / 8);        // 14 buckets per lane
    u32 mysum = 0;
#pragma unroll
    for (int t = 0; t < NBK / 8; ++t)
        mysum += (hist[hb + b0 + t] >> sh) & 0xFFFFu;
    u32 csum = mysum;
#pragma unroll
    for (int o = 1; o < 8; o <<= 1) {
        const u32 t = __shfl_up(csum, o, 8);
        if (h >= o) csum += t;
    }
    const u32 cumBefore = csum - mysum;
    const bool cross = (cumBefore < 16u) && (cumBefore + mysum >= 16u);
    int T = 0;
    if (cross) {
        u32 c = cumBefore; int t = 0;
        while (true) {
            const u32 v = (hist[hb + b0 + t] >> sh) & 0xFFFFu;
            if (c + v >= 16u) break;
            c += v; ++t;
        }
        T = b0 + t;
    }
    const u64 bal = __ballot(cross);
    const int gbase = lane & ~7;
    const int crossl = gbase + (__ffsll(bal >> gbase) - 1);
    T = __shfl(T, crossl, 64);
    const u32 smax = HBASE + (u32)T + 1u;   // one-bucket slack

    // ---- pass 2: collect superset ----
#pragma unroll 1
    for (int cc = 0; cc < 64; ++cc) {
#pragma unroll
        for (int s = 0; s < 8; ++s) {
            const int j = cc * 64 + s * 8 + h;
            const float2 xy = pxy[j];
            const float  z  = pz[j];
            const float dx = __fsub_rn(mx, xy.x);
            const float dy = __fsub_rn(my, xy.y);
            const float dz = __fsub_rn(mz, z);
            const float d  = __fmaf_rn(dz, dz, __fmaf_rn(dy, dy, __fmul_rn(dx, dx)));
            const u32 sb = __float_as_uint(d) >> 20;
            if (sb <= smax) {
                const u32 old = atomicAdd(&cnt[qloc], 1u);
                if (old < (u32)LCAP) list[qloc][old] = (u16)j;
            }
        }
    }

    // ---- exact re-rank of <=64 survivors: key = d_bits<<12 | j (f64) ----
    const int c = (int)min(cnt[qloc], (u32)LCAP);
    double kd[8];
#pragma unroll
    for (int s = 0; s < 8; ++s) {
        const int m = h * 8 + s;
        const int j = (m < c) ? (int)list[qloc][m] : 0;
        const float2 xy = pxy[j];
        const float d = dist2(mx, my, mz, xy.x, xy.y, pz[j]);
        const u64 key = ((u64)__float_as_uint(d) << 12) | (unsigned)j;
        kd[s] = (m < c) ? __builtin_bit_cast(double, key) : 1.0;  // sentinel
    }
    // local Batcher sort-8 ascending (19 CE)
    ced(kd[0],kd[1]); ced(kd[2],kd[3]); ced(kd[4],kd[5]); ced(kd[6],kd[7]);
    ced(kd[0],kd[2]); ced(kd[1],kd[3]); ced(kd[4],kd[6]); ced(kd[5],kd[7]);
    ced(kd[1],kd[2]); ced(kd[5],kd[6]);
    ced(kd[0],kd[4]); ced(kd[1],kd[5]); ced(kd[2],kd[6]); ced(kd[3],kd[7]);
    ced(kd[2],kd[4]); ced(kd[3],kd[5]);
    ced(kd[1],kd[2]); ced(kd[3],kd[4]); ced(kd[5],kd[6]);
    // distributed bitonic merge over 8 lanes -> sorted-64 (pattern verified
    // at 4-reg (r1+) and 16-reg (r2+) widths)
    {   // round 1: xor1 reversed + local merge-8
        double P[8];
#pragma unroll
        for (int s = 0; s < 8; ++s) P[s] = __shfl_xor(kd[s], 1, 64);
        const bool lo = (h & 1) == 0;
#pragma unroll
        for (int s = 0; s < 8; ++s) {
            const double o = P[7 - s];
            kd[s] = lo ? __builtin_fmin(kd[s], o) : __builtin_fmax(kd[s], o);
        }
        ced(kd[0],kd[4]); ced(kd[1],kd[5]); ced(kd[2],kd[6]); ced(kd[3],kd[7]);
        ced(kd[0],kd[2]); ced(kd[1],kd[3]); ced(kd[4],kd[6]); ced(kd[5],kd[7]);
        ced(kd[0],kd[1]); ced(kd[2],kd[3]); ced(kd[4],kd[5]); ced(kd[6],kd[7]);
    }
    {   // round 2: xor3 reversed, xor1 same-reg, local merge-8
        double P[8];
#pragma unroll
        for (int s = 0; s < 8; ++s) P[s] = __shfl_xor(kd[s], 3, 64);
        const bool lo = (h & 2) == 0;
#pragma unroll
        for (int s = 0; s < 8; ++s) {
            const double o = P[7 - s];
            kd[s] = lo ? __builtin_fmin(kd[s], o) : __builtin_fmax(kd[s], o);
        }
#pragma unroll
        for (int s = 0; s < 8; ++s) P[s] = __shfl_xor(kd[s], 1, 64);
        const bool lo1 = (h & 1) == 0;
#pragma unroll
        for (int s = 0; s < 8; ++s) {
            const double o = P[s];
            kd[s] = lo1 ? __builtin_fmin(kd[s], o) : __builtin_fmax(kd[s], o);
        }
        ced(kd[0],kd[4]); ced(kd[1],kd[5]); ced(kd[2],kd[6]); ced(kd[3],kd[7]);
        ced(kd[0],kd[2]); ced(kd[1],kd[3]); ced(kd[4],kd[6]); ced(kd[5],kd[7]);
        ced(kd[0],kd[1]); ced(kd[2],kd[3]); ced(kd[4],kd[5]); ced(kd[6],kd[7]);
    }
    {   // round 3: xor7 reversed, xor2, xor1, local merge-8
        double P[8];
#pragma unroll
        for (int s = 0; s < 8; ++s) P[s] = __shfl_xor(kd[s], 7, 64);
        const bool lo = (h & 4) == 0;
#pragma unroll
        for (int s = 0; s < 8; ++s) {
            const double o = P[7 - s];
            kd[s] = lo ? __builtin_fmin(kd[s], o) : __builtin_fmax(kd[s], o);
        }
#pragma unroll
        for (int s = 0; s < 8; ++s) P[s] = __shfl_xor(kd[s], 2, 64);
        const bool lo2 = (h & 2) == 0;
#pragma unroll
        for (int s = 0; s < 8; ++s) {
            const double o = P[s];
            kd[s] = lo2 ? __builtin_fmin(kd[s], o) : __builtin_fmax(kd[s], o);
        }
#pragma unroll
        for (int s = 0; s < 8; ++s) P[s] = __shfl_xor(kd[s], 1, 64);
        const bool lo1 = (h & 1) == 0;
#pragma unroll
        for (int s = 0; s < 8; ++s) {
            const double o = P[s];
            kd[s] = lo1 ? __builtin_fmin(kd[s], o) : __builtin_fmax(kd[s], o);
        }
        ced(kd[0],kd[4]); ced(kd[1],kd[5]); ced(kd[2],kd[6]); ced(kd[3],kd[7]);
        ced(kd[0],kd[2]); ced(kd[1],kd[3]); ced(kd[4],kd[6]); ced(kd[5],kd[7]);
        ced(kd[0],kd[1]); ced(kd[2],kd[3]); ced(kd[4],kd[5]); ced(kd[6],kd[7]);
    }

    // lanes h<2 hold final top-16 (rank = h*8+s): epilogue
    const size_t gq = (size_t)b * LQ + l;
    if (h < 2) {
        const float4 f0 = fb[l * 3 + 0];
        const float4 f1 = fb[l * 3 + 1];
        const float4 f2 = fb[l * 3 + 2];
        const float R00 = f0.w, R01 = f1.x, R02 = f1.y;
        const float R10 = f1.z, R11 = f1.w, R12 = f2.x;
        const float R20 = f2.y, R21 = f2.z, R22 = f2.w;
        float e[24];
#pragma unroll
        for (int s = 0; s < 8; ++s) {
            const u64 bits = __builtin_bit_cast(u64, kd[s]);
            const int j = (int)(bits & 0xFFFu);
            nbrs[qloc][h * 8 + s] = j;
            const float2 xy = pxy[j];
            const float dx = xy.x - mx;       // delta = nbr_center - center
            const float dy = xy.y - my;
            const float dz = pz[j] - mz;
            e[s * 3 + 0] = dx * R00 + dy * R10 + dz * R20;
            e[s * 3 + 1] = dx * R01 + dy * R11 + dz * R21;
            e[s * 3 + 2] = dx * R02 + dy * R12 + dz * R22;
        }
        float4* eo = (float4*)(out_e + gq * 48 + h * 24);
#pragma unroll
        for (int t = 0; t < 6; ++t) eo[t] = ((const float4*)e)[t];
    }

    // ---- fused gather (per wave: its 8 queries x 16 nbrs x 32 float4) ----
    const float4* ab = attr4 + (((size_t)b) << 12) * 32;
    const size_t obase = ((size_t)b * LQ + (size_t)qblk * QPB + (size_t)wv * 8) * 512;
#pragma unroll 4
    for (int it = 0; it < 64; ++it) {
        const int idx = it * 64 + lane;      // 0..4095
        const int qw  = idx >> 9;            // 0..7 within-wave query
        const int r   = idx & 511;
        const int k   = r >> 5, d4 = r & 31;
        const int nb  = nbrs[wv * 8 + qw][k];
        const float4 v = ab[(size_t)nb * 32 + d4];
        nfloat4 nv = {v.x, v.y, v.z, v.w};
        __builtin_nontemporal_store(nv, &outg4[obase + idx]);
    }
}

extern "C" void kernel_launch(void* const* d_in, const int* in_sizes, int n_in,
                              void* d_out, int out_size, void* d_ws, size_t ws_size,
                              hipStream_t stream)
{
    const float* frame = (const float*)d_in[0];   // (8,4096,4,3) f32
    const float* attr  = (const float*)d_in[1];   // (8,4096,128) f32
    float* out = (float*)d_out;                   // euclidian ++ gathered

    nfloat4* outg4 = (nfloat4*)(out + (size_t)BQ * LQ * KNB * 3);
    knn_fused_kernel<<<BQ * BPB, TPB, 0, stream>>>(
        (const float4*)frame, (const float4*)attr, out, outg4);
}

// Round 8
// 321.487 us; speedup vs baseline: 1.2382x; 1.2382x over previous
//
#include <hip/hip_runtime.h>
#include <stdint.h>

typedef unsigned long long u64;
typedef float nfloat4 __attribute__((ext_vector_type(4)));  // native vec for nt-store

#define LQ   4096
#define BQ   8
#define KNB  16
#define TPB  512
#define QPB  64                  // queries per block, 8 lanes each
#define BPB  (LQ / QPB)          // 64 blocks per batch

// u32 compare-exchange (full-rate v_min_u32/v_max_u32)
__device__ __forceinline__ void ceu(uint32_t &a, uint32_t &b) {
    const uint32_t mn = a < b ? a : b;
    const uint32_t mx = a < b ? b : a;
    a = mn; b = mx;
}
// f64 compare-exchange (exact 44-bit keys as positive denormals)
__device__ __forceinline__ void ced(double &a, double &b) {
    const double mn = __builtin_fmin(a, b);
    const double mx = __builtin_fmax(a, b);
    a = mn; b = mx;
}
// bit-exact vs reference: no FMA, sum order (x^2+y^2)+z^2  (re-rank only)
__device__ __forceinline__ float dist2(float mx, float my, float mz,
                                       float px, float py, float pz) {
    const float dx = __fsub_rn(mx, px);
    const float dy = __fsub_rn(my, py);
    const float dz = __fsub_rn(mz, pz);
    return __fadd_rn(__fadd_rn(__fmul_rn(dx, dx), __fmul_rn(dy, dy)),
                     __fmul_rn(dz, dz));
}

// Scan key: (f32 dist bits truncated to top 20) << 12 | j.  Monotone in d, so a
// true top-16 member has <=15 strictly-smaller keys + ~0.01 expected "bucket
// mates" (same 2^-11-relative bucket, smaller j). Keeping per-query top-32
// makes a wrong drop require >=17 mates (prob ~0); the 32 survivors are
// re-ranked exactly with the proven ((u64)d_bits<<12)|j keys.  FMA in the scan
// distance only perturbs keys by ~1-2 ulp << the 4096-ulp truncation bucket;
// this scan-FMA + exact-re-rank construction was harness-verified (r4-r7).
//
// XCD locality: b = blockIdx & 7 so (with %8 XCD round-robin dispatch) each
// batch's 64 blocks land on one XCD (64 = 32 CU x 2 blocks, exact fit) and its
// attr table (2 MB) + frame stay L2-resident. r7 counters showed FETCH 95 MB
// vs ~18 MB compulsory (6x over-fetch) with the old b = blockIdx/64 mapping.

__global__ __launch_bounds__(TPB) void knn_fused_kernel(
    const float4* __restrict__ frame4,   // (B, L, 3) float4 view of (B,L,4,3)
    const float4* __restrict__ attr4,    // (B, L, 32) float4 view of (B,L,128)
    float* __restrict__ out_e,           // (B, L, 16, 3)
    nfloat4* __restrict__ outg4)         // (B, L, 16, 32) float4
{
    __shared__ float4 cpos[LQ];                // 64 KB (w = R00, unused in scan)
    __shared__ unsigned short surv[QPB][32];   // 4 KB  per-query top-32 cand idx
    __shared__ int nbrs[QPB][KNB];             // 4 KB  final neighbor idx
    // total 72 KB -> exactly 2 blocks/CU, grid 512 = 2*256: zero tail

    const int b    = blockIdx.x & 7;           // batch -> XCD (see note above)
    const int qblk = blockIdx.x >> 3;          // 0..63 query chunk
    const int tid  = threadIdx.x;

    const float4* fb = frame4 + (size_t)b * LQ * 3;
    for (int j = tid; j < LQ; j += TPB) cpos[j] = fb[j * 3];
    __syncthreads();   // only barrier: waves are independent afterwards

    const int qloc = tid >> 3;           // 0..63
    const int h    = tid & 7;            // sub-stream within query
    const int l    = qblk * QPB + qloc;
    const float4 me = cpos[l];
    const float mx = me.x, my = me.y, mz = me.z;

    // per-lane running sorted-ascending top-16 of 32-bit keys
    uint32_t R[16];
#pragma unroll
    for (int i = 0; i < 16; ++i) R[i] = 0xFFFFFFFFu;

#pragma unroll 1
    for (int cc = 0; cc < 64; ++cc) {
        uint32_t K[8];
#pragma unroll
        for (int s = 0; s < 8; ++s) {
            const int j = cc * 64 + s * 8 + h;
            const float4 p = cpos[j];            // one ds_read_b128
            const float dx = __fsub_rn(mx, p.x);
            const float dy = __fsub_rn(my, p.y);
            const float dz = __fsub_rn(mz, p.z);
            const float d  = __fmaf_rn(dz, dz, __fmaf_rn(dy, dy, __fmul_rn(dx, dx)));
            K[s] = (__float_as_uint(d) & 0xFFFFF000u) | (unsigned)j;
        }
        // Batcher odd-even mergesort-8 (19 comparators), ascending
        ceu(K[0],K[1]); ceu(K[2],K[3]); ceu(K[4],K[5]); ceu(K[6],K[7]);
        ceu(K[0],K[2]); ceu(K[1],K[3]); ceu(K[4],K[6]); ceu(K[5],K[7]);
        ceu(K[1],K[2]); ceu(K[5],K[6]);
        ceu(K[0],K[4]); ceu(K[1],K[5]); ceu(K[2],K[6]); ceu(K[3],K[7]);
        ceu(K[2],K[4]); ceu(K[3],K[5]);
        ceu(K[1],K[2]); ceu(K[3],K[4]); ceu(K[5],K[6]);
        // bottom-16 of (R asc-16 ∪ K asc-8): min-layer then bitonic merge-16
#pragma unroll
        for (int t = 0; t < 8; ++t) {
            const uint32_t x = R[8 + t], y = K[7 - t];
            R[8 + t] = x < y ? x : y;
        }
#pragma unroll
        for (int g = 8; g >= 1; g >>= 1)
#pragma unroll
            for (int i = 0; i < 16; ++i)
                if ((i & g) == 0) ceu(R[i], R[i + g]);
    }

    // ---- distributed cross-lane merge over the query's 8 lanes, keeping ALL
    // 128 elements: after this, position p = h*16+i is fully sorted ascending.
    {
        uint32_t P[16];
#pragma unroll
        for (int i = 0; i < 16; ++i) P[i] = __shfl_xor(R[i], 1, 64);
        const bool lo1 = (h & 1) == 0;
#pragma unroll
        for (int i = 0; i < 16; ++i) {
            const uint32_t o = P[15 - i];
            R[i] = lo1 ? (R[i] < o ? R[i] : o) : (R[i] > o ? R[i] : o);
        }
#pragma unroll
        for (int g = 8; g >= 1; g >>= 1)
#pragma unroll
            for (int i = 0; i < 16; ++i)
                if ((i & g) == 0) ceu(R[i], R[i + g]);
    }
    {
        uint32_t P[16];
#pragma unroll
        for (int i = 0; i < 16; ++i) P[i] = __shfl_xor(R[i], 3, 64);
        const bool lo2 = (h & 2) == 0;
#pragma unroll
        for (int i = 0; i < 16; ++i) {
            const uint32_t o = P[15 - i];
            R[i] = lo2 ? (R[i] < o ? R[i] : o) : (R[i] > o ? R[i] : o);
        }
#pragma unroll
        for (int i = 0; i < 16; ++i) P[i] = __shfl_xor(R[i], 1, 64);
        const bool lo1 = (h & 1) == 0;
#pragma unroll
        for (int i = 0; i < 16; ++i) {
            const uint32_t o = P[i];
            R[i] = lo1 ? (R[i] < o ? R[i] : o) : (R[i] > o ? R[i] : o);
        }
#pragma unroll
        for (int g = 8; g >= 1; g >>= 1)
#pragma unroll
            for (int i = 0; i < 16; ++i)
                if ((i & g) == 0) ceu(R[i], R[i + g]);
    }
    {
        uint32_t P[16];
#pragma unroll
        for (int i = 0; i < 16; ++i) P[i] = __shfl_xor(R[i], 7, 64);
        const bool lo4 = (h & 4) == 0;
#pragma unroll
        for (int i = 0; i < 16; ++i) {
            const uint32_t o = P[15 - i];
            R[i] = lo4 ? (R[i] < o ? R[i] : o) : (R[i] > o ? R[i] : o);
        }
#pragma unroll
        for (int i = 0; i < 16; ++i) P[i] = __shfl_xor(R[i], 2, 64);
        const bool lo2 = (h & 2) == 0;
#pragma unroll
        for (int i = 0; i < 16; ++i) {
            const uint32_t o = P[i];
            R[i] = lo2 ? (R[i] < o ? R[i] : o) : (R[i] > o ? R[i] : o);
        }
#pragma unroll
        for (int i = 0; i < 16; ++i) P[i] = __shfl_xor(R[i], 1, 64);
        const bool lo1 = (h & 1) == 0;
#pragma unroll
        for (int i = 0; i < 16; ++i) {
            const uint32_t o = P[i];
            R[i] = lo1 ? (R[i] < o ? R[i] : o) : (R[i] > o ? R[i] : o);
        }
#pragma unroll
        for (int g = 8; g >= 1; g >>= 1)
#pragma unroll
            for (int i = 0; i < 16; ++i)
                if ((i & g) == 0) ceu(R[i], R[i + g]);
    }

    // lanes 0,1 hold the query's top-32 keys -> publish candidate indices
    if (h < 2) {
#pragma unroll
        for (int i = 0; i < 16; ++i)
            surv[qloc][h * 16 + i] = (unsigned short)(R[i] & 0xFFFu);
    }

    // ---- exact re-rank of the 32 survivors with 44-bit keys (f64 denormals).
    // 4 keys per lane; distributed bitonic merge to sorted-32 over 8 lanes.
    double kd[4];
#pragma unroll
    for (int s = 0; s < 4; ++s) {
        const int j = surv[qloc][h * 4 + s];
        const float4 p = cpos[j];
        const float d = dist2(mx, my, mz, p.x, p.y, p.z);
        kd[s] = __builtin_bit_cast(double,
                 ((u64)__float_as_uint(d) << 12) | (unsigned)j);
    }
    ced(kd[0],kd[1]); ced(kd[2],kd[3]); ced(kd[0],kd[2]); ced(kd[1],kd[3]); ced(kd[1],kd[2]);
    {
        double P[4];
#pragma unroll
        for (int s = 0; s < 4; ++s) P[s] = __shfl_xor(kd[s], 1, 64);
        const bool lo1 = (h & 1) == 0;
#pragma unroll
        for (int s = 0; s < 4; ++s) {
            const double o = P[3 - s];
            kd[s] = lo1 ? __builtin_fmin(kd[s], o) : __builtin_fmax(kd[s], o);
        }
        ced(kd[0],kd[2]); ced(kd[1],kd[3]); ced(kd[0],kd[1]); ced(kd[2],kd[3]);
    }
    {
        double P[4];
#pragma unroll
        for (int s = 0; s < 4; ++s) P[s] = __shfl_xor(kd[s], 3, 64);
        const bool lo2 = (h & 2) == 0;
#pragma unroll
        for (int s = 0; s < 4; ++s) {
            const double o = P[3 - s];
            kd[s] = lo2 ? __builtin_fmin(kd[s], o) : __builtin_fmax(kd[s], o);
        }
#pragma unroll
        for (int s = 0; s < 4; ++s) P[s] = __shfl_xor(kd[s], 1, 64);
        const bool lo1 = (h & 1) == 0;
#pragma unroll
        for (int s = 0; s < 4; ++s) {
            const double o = P[s];
            kd[s] = lo1 ? __builtin_fmin(kd[s], o) : __builtin_fmax(kd[s], o);
        }
        ced(kd[0],kd[2]); ced(kd[1],kd[3]); ced(kd[0],kd[1]); ced(kd[2],kd[3]);
    }
    {
        double P[4];
#pragma unroll
        for (int s = 0; s < 4; ++s) P[s] = __shfl_xor(kd[s], 7, 64);
        const bool lo4 = (h & 4) == 0;
#pragma unroll
        for (int s = 0; s < 4; ++s) {
            const double o = P[3 - s];
            kd[s] = lo4 ? __builtin_fmin(kd[s], o) : __builtin_fmax(kd[s], o);
        }
#pragma unroll
        for (int s = 0; s < 4; ++s) P[s] = __shfl_xor(kd[s], 2, 64);
        const bool lo2 = (h & 2) == 0;
#pragma unroll
        for (int s = 0; s < 4; ++s) {
            const double o = P[s];
            kd[s] = lo2 ? __builtin_fmin(kd[s], o) : __builtin_fmax(kd[s], o);
        }
#pragma unroll
        for (int s = 0; s < 4; ++s) P[s] = __shfl_xor(kd[s], 1, 64);
        const bool lo1 = (h & 1) == 0;
#pragma unroll
        for (int s = 0; s < 4; ++s) {
            const double o = P[s];
            kd[s] = lo1 ? __builtin_fmin(kd[s], o) : __builtin_fmax(kd[s], o);
        }
        ced(kd[0],kd[2]); ced(kd[1],kd[3]); ced(kd[0],kd[1]); ced(kd[2],kd[3]);
    }

    // lanes h<4 hold final top-16 (position h*4+s): epilogue
    const size_t gq = (size_t)b * LQ + l;
    if (h < 4) {
        const float4 f1 = fb[l * 3 + 1];
        const float4 f2 = fb[l * 3 + 2];
        const float R00 = me.w, R01 = f1.x, R02 = f1.y;
        const float R10 = f1.z, R11 = f1.w, R12 = f2.x;
        const float R20 = f2.y, R21 = f2.z, R22 = f2.w;
        float e[12];
#pragma unroll
        for (int s = 0; s < 4; ++s) {
            const u64 bits = __builtin_bit_cast(u64, kd[s]);
            const int j = (int)(bits & 0xFFFu);
            nbrs[qloc][h * 4 + s] = j;
            const float4 p = cpos[j];
            const float dx = p.x - mx;        // delta = nbr_center - center
            const float dy = p.y - my;
            const float dz = p.z - mz;
            e[s * 3 + 0] = dx * R00 + dy * R10 + dz * R20;
            e[s * 3 + 1] = dx * R01 + dy * R11 + dz * R21;
            e[s * 3 + 2] = dx * R02 + dy * R12 + dz * R22;
        }
        float4* eo = (float4*)(out_e + gq * 48 + h * 12);
        float4 v0 = {e[0], e[1], e[2],  e[3]};
        float4 v1 = {e[4], e[5], e[6],  e[7]};
        float4 v2 = {e[8], e[9], e[10], e[11]};
        eo[0] = v0; eo[1] = v1; eo[2] = v2;
    }

    // ---- fused gather (per wave: its 8 queries x 16 nbrs x 32 float4) ----
    const float4* ab = attr4 + (((size_t)b) << 12) * 32;
    const int wv = tid >> 6, lane = tid & 63;    // wv = 0..7
    const size_t obase = ((size_t)b * LQ + (size_t)qblk * QPB + (size_t)wv * 8) * 512;
#pragma unroll 8
    for (int it = 0; it < 64; ++it) {
        const int idx = it * 64 + lane;      // 0..4095
        const int qw  = idx >> 9;            // 0..7 within-wave query
        const int r   = idx & 511;
        const int k   = r >> 5, d4 = r & 31;
        const int nb  = nbrs[wv * 8 + qw][k];
        const float4 v = ab[(size_t)nb * 32 + d4];
        nfloat4 nv = {v.x, v.y, v.z, v.w};
        __builtin_nontemporal_store(nv, &outg4[obase + idx]);
    }
}

extern "C" void kernel_launch(void* const* d_in, const int* in_sizes, int n_in,
                              void* d_out, int out_size, void* d_ws, size_t ws_size,
                              hipStream_t stream)
{
    const float* frame = (const float*)d_in[0];   // (8,4096,4,3) f32
    const float* attr  = (const float*)d_in[1];   // (8,4096,128) f32
    float* out = (float*)d_out;                   // euclidian ++ gathered

    nfloat4* outg4 = (nfloat4*)(out + (size_t)BQ * LQ * KNB * 3);
    knn_fused_kernel<<<BQ * BPB, TPB, 0, stream>>>(
        (const float4*)frame, (const float4*)attr, out, outg4);
}